// Round 1
// baseline (160.919 us; speedup 1.0000x reference)
//
#include <hip/hip_runtime.h>
#include <math.h>

#define HW_ (512 * 512)   // 2^18
#define C_ 64
#define K_ 16
#define B_ 8

// Transpose conv_w [K][C] -> wt [C][K] so each 4-channel chunk of weights is
// 64 contiguous floats (scalarizable to s_load_dwordx16 in the main kernel).
__global__ __launch_bounds__(256) void transpose_w_kernel(const float* __restrict__ w,
                                                          float* __restrict__ wt) {
    int i = blockIdx.x * blockDim.x + threadIdx.x;  // 0..1023
    if (i < K_ * C_) {
        int k = i >> 6;   // i / 64
        int c = i & 63;   // i % 64
        wt[c * K_ + k] = w[i];
    }
}

__global__ __launch_bounds__(256) void quantizer_kernel(
    const float* __restrict__ x,        // [B][C][HW]
    const float* __restrict__ wt,       // [C][K] (transposed weights)
    const float* __restrict__ bias,     // [K]
    const float* __restrict__ palette,  // [K][3]
    const float* __restrict__ unif,     // [B*HW][K]
    float* __restrict__ out)            // [B][3][HW]
{
    const int total = B_ * HW_;
    int tid = blockIdx.x * blockDim.x + threadIdx.x;
    int stride = gridDim.x * blockDim.x;

    for (int p = tid; p < total; p += stride) {
        int b = p >> 18;            // p / HW_
        int hw = p & (HW_ - 1);     // p % HW_
        const float* xp = x + ((size_t)b * C_) * (size_t)HW_ + (size_t)hw;

        // ---- logits: acc[k] = bias[k] + sum_c x[c] * W[k][c] ----
        float acc[K_];
        #pragma unroll
        for (int k = 0; k < K_; ++k) acc[k] = bias[k];

        for (int c = 0; c < C_; c += 4) {
            float x0 = xp[(size_t)(c + 0) * HW_];
            float x1 = xp[(size_t)(c + 1) * HW_];
            float x2 = xp[(size_t)(c + 2) * HW_];
            float x3 = xp[(size_t)(c + 3) * HW_];
            const float* wp = wt + c * K_;  // 64 contiguous uniform floats
            #pragma unroll
            for (int k = 0; k < K_; ++k) {
                float a = acc[k];
                a = fmaf(x0, wp[k],          a);
                a = fmaf(x1, wp[K_ + k],     a);
                a = fmaf(x2, wp[2 * K_ + k], a);
                a = fmaf(x3, wp[3 * K_ + k], a);
                acc[k] = a;
            }
        }

        // ---- log_softmax pieces (mimic jax: (x - m) - log(sum(exp(x - m)))) ----
        float m = acc[0];
        #pragma unroll
        for (int k = 1; k < K_; ++k) m = fmaxf(m, acc[k]);
        float s = 0.0f;
        #pragma unroll
        for (int k = 0; k < K_; ++k) s += expf(acc[k] - m);
        float ls = logf(s);

        // ---- gumbel-max argmax (first occurrence on ties, ascending k) ----
        const float4* up4 = reinterpret_cast<const float4*>(unif + (size_t)p * K_);
        float u[K_];
        #pragma unroll
        for (int q = 0; q < 4; ++q) {
            float4 v = up4[q];
            u[q * 4 + 0] = v.x; u[q * 4 + 1] = v.y;
            u[q * 4 + 2] = v.z; u[q * 4 + 3] = v.w;
        }
        float best = -INFINITY;
        int bi = 0;
        #pragma unroll
        for (int k = 0; k < K_; ++k) {
            float g = -logf(-logf(u[k] + 1e-20f) + 1e-20f);
            float t = (acc[k] - m) - ls + g;   // logp + gumbel, same fp order as ref
            if (t > best) { best = t; bi = k; }
        }

        // ---- output = palette[idx] (straight-through == discrete in value) ----
        float pr = palette[bi * 3 + 0];
        float pg = palette[bi * 3 + 1];
        float pb = palette[bi * 3 + 2];
        size_t obase = (size_t)b * 3 * HW_ + (size_t)hw;
        out[obase]                    = pr;
        out[obase + (size_t)HW_]      = pg;
        out[obase + 2 * (size_t)HW_]  = pb;
    }
}

extern "C" void kernel_launch(void* const* d_in, const int* in_sizes, int n_in,
                              void* d_out, int out_size, void* d_ws, size_t ws_size,
                              hipStream_t stream) {
    const float* x       = (const float*)d_in[0];
    const float* conv_w  = (const float*)d_in[1];
    const float* conv_b  = (const float*)d_in[2];
    const float* palette = (const float*)d_in[3];
    const float* unif    = (const float*)d_in[4];
    float* out = (float*)d_out;
    float* wt  = (float*)d_ws;   // needs K_*C_*4 = 4 KiB scratch

    hipLaunchKernelGGL(transpose_w_kernel, dim3(4), dim3(256), 0, stream, conv_w, wt);

    const int blocks = 2048;     // 524288 threads, 4 pixels each (grid-stride)
    hipLaunchKernelGGL(quantizer_kernel, dim3(blocks), dim3(256), 0, stream,
                       x, wt, conv_b, palette, unif, out);
}